// Round 1
// baseline (135.166 us; speedup 1.0000x reference)
//
#include <hip/hip_runtime.h>
#include <hip/hip_bf16.h>
#include <stdint.h>

#define NN 2048
#define LOG2NN 11
#define GK 2048      // contraction dim for both GEMMs
#define GNC 2048     // output column count for both GEMMs

typedef __bf16 bf16x8 __attribute__((ext_vector_type(8)));
typedef float f32x4 __attribute__((ext_vector_type(4)));

// round-to-nearest-even f32 -> bf16 bits
__device__ __forceinline__ ushort f2bf(float f) {
  uint32_t x = __float_as_uint(f);
  uint32_t r = (x + 0x7fffu + ((x >> 16) & 1u)) >> 16;
  return (ushort)r;
}

// ---------------------------------------------------------------- zero ws
__global__ void zero_ws_kernel(uint4* __restrict__ aoff, float* __restrict__ uW,
                               int* __restrict__ ecnt) {
  int i = blockIdx.x * blockDim.x + threadIdx.x;  // 524288 threads = 8.4MB/16B
  aoff[i] = make_uint4(0u, 0u, 0u, 0u);
  if (i < NN) uW[i] = 0.f;
  if (i == 0) *ecnt = 0;
}

// ---------------------------------------------------------------- softmax + scatter
__device__ __forceinline__ int lower_bound32(const int* __restrict__ a, int n, int v) {
  int lo = 0, hi = n;
  while (lo < hi) {
    int mid = (lo + hi) >> 1;
    if (a[mid] < v) lo = mid + 1; else hi = mid;
  }
  return lo;
}

// one wave per row r: segmented softmax over sorted edge list, scatter bf16
// off-diagonal values into AoffT[n][k] (= A_off[k][n]), diag + empty flags.
__global__ void softmax_scatter_kernel(const int* __restrict__ idx, const float* __restrict__ e,
                                       int nnz, ushort* __restrict__ AoffT,
                                       float* __restrict__ diag, int* __restrict__ empty,
                                       int* __restrict__ ecnt) {
  int r = blockIdx.x;
  int lane = threadIdx.x;
  int lo = lower_bound32(idx, nnz, r << LOG2NN);
  int hi = lower_bound32(idx, nnz, (r + 1) << LOG2NN);
  if (hi <= lo) {  // empty row: softmax of all-equal NEG -> uniform 1/NN
    if (lane == 0) { diag[r] = 1.0f / NN; empty[r] = 1; atomicAdd(ecnt, 1); }
    return;
  }
  float m = -3.0e38f;
  for (int j = lo + lane; j < hi; j += 64) m = fmaxf(m, e[j]);
#pragma unroll
  for (int s = 32; s >= 1; s >>= 1) m = fmaxf(m, __shfl_xor(m, s));
  float sum = 0.f;
  for (int j = lo + lane; j < hi; j += 64) sum += expf(e[j] - m);
#pragma unroll
  for (int s = 32; s >= 1; s >>= 1) sum += __shfl_xor(sum, s);
  float inv = 1.0f / sum;
  float dv = 0.f;
  for (int j = lo + lane; j < hi; j += 64) {
    int c = idx[j] & (NN - 1);
    float v = expf(e[j] - m) * inv;
    if (c == r) dv = v;                                   // diagonal term
    else AoffT[(size_t)c * NN + r] = f2bf(v);             // AoffT[col][row]
  }
#pragma unroll
  for (int s = 32; s >= 1; s >>= 1) dv += __shfl_xor(dv, s);
  if (lane == 0) { diag[r] = dv; empty[r] = 0; }
}

// uW[p] = (1/NN) * sum_{empty k} W2[p,k]  (dead path unless an empty row exists)
__global__ void uw_kernel(const float* __restrict__ W2, const int* __restrict__ empty,
                          const int* __restrict__ ecnt, float* __restrict__ uW) {
  if (*ecnt == 0) return;
  int p = blockIdx.x * blockDim.x + threadIdx.x;
  if (p >= NN) return;
  float s = 0.f;
  for (int k = 0; k < NN; ++k)
    if (empty[k]) s += W2[(size_t)p * NN + k];
  uW[p] = s * (1.0f / NN);
}

// ---------------------------------------------------------------- f32 -> bf16 (vectorized)
__global__ void f32_to_bf16_kernel(const float* __restrict__ in, ushort* __restrict__ out,
                                   int n8) {
  int i = blockIdx.x * blockDim.x + threadIdx.x;
  if (i >= n8) return;
  const float4* in4 = reinterpret_cast<const float4*>(in);
  float4 a = in4[2 * i];
  float4 b = in4[2 * i + 1];
  uint4 o;
  o.x = (uint32_t)f2bf(a.x) | ((uint32_t)f2bf(a.y) << 16);
  o.y = (uint32_t)f2bf(a.z) | ((uint32_t)f2bf(a.w) << 16);
  o.z = (uint32_t)f2bf(b.x) | ((uint32_t)f2bf(b.y) << 16);
  o.w = (uint32_t)f2bf(b.z) | ((uint32_t)f2bf(b.w) << 16);
  reinterpret_cast<uint4*>(out)[i] = o;
}

// ---------------------------------------------------------------- bf16 bt-GEMM (m97 structure)
// C[row, col] = sum_k A[row, k] * Bt[col, k];  A:[M][2048] bf16, Bt:[2048][2048] bf16.
// 128x128 tile, 4 waves (2x2), BK=32, global_load_lds width 16, 16x16x32 MFMA.
// EPI=0: store fp32 to Cf.  EPI=1: add diag/empty corrections, store bf16 to Cb
//        (row = n index, col = p index of Wfused^T).
__device__ __forceinline__ void gload_lds16(const ushort* g, char* l) {
  __builtin_amdgcn_global_load_lds(
      (__attribute__((address_space(1))) uint32_t*)(uintptr_t)g,
      (__attribute__((address_space(3))) uint32_t*)l, 16, 0, 0);
}

template <int EPI>
__global__ __launch_bounds__(256)
void gemm_bt_kernel(const ushort* __restrict__ A, const ushort* __restrict__ Bt,
                    float* __restrict__ Cf, ushort* __restrict__ Cb,
                    const float* __restrict__ diag, const int* __restrict__ empty,
                    const float* __restrict__ uW, const float* __restrict__ W1f,
                    const float* __restrict__ W2f) {
  __shared__ ushort As[128 * 32];
  __shared__ ushort Bs[128 * 32];
  const int t = threadIdx.x;
  const int wid = t >> 6;
  const int lane = t & 63;
  const int m0 = blockIdx.y * 128;
  const int n0 = blockIdx.x * 128;
  const int wm = wid >> 1, wn = wid & 1;

  f32x4 acc[4][4] = {};

  // staging: thread t covers 16B chunk t of each 64-row half-tile (rows of 64B)
  const ushort* Ag0 = A + (size_t)(m0 + (t >> 2)) * GK + (t & 3) * 8;
  const ushort* Ag1 = Ag0 + (size_t)64 * GK;
  const ushort* Bg0 = Bt + (size_t)(n0 + (t >> 2)) * GK + (t & 3) * 8;
  const ushort* Bg1 = Bg0 + (size_t)64 * GK;
  char* AsW = (char*)As + wid * 1024;  // wave-uniform LDS base (+ lane*16 by HW)
  char* BsW = (char*)Bs + wid * 1024;

  const int fr = lane & 15, fg = lane >> 4;
  const ushort* ArdA = As + (size_t)(wm * 64 + fr) * 32 + fg * 8;
  const ushort* ArdB = Bs + (size_t)(wn * 64 + fr) * 32 + fg * 8;

  for (int kt = 0; kt < GK; kt += 32) {
    gload_lds16(Ag0 + kt, AsW);
    gload_lds16(Ag1 + kt, AsW + 4096);
    gload_lds16(Bg0 + kt, BsW);
    gload_lds16(Bg1 + kt, BsW + 4096);
    __syncthreads();  // drains vmcnt before barrier
    bf16x8 af[4], bb[4];
#pragma unroll
    for (int i = 0; i < 4; ++i) af[i] = *reinterpret_cast<const bf16x8*>(ArdA + i * 16 * 32);
#pragma unroll
    for (int i = 0; i < 4; ++i) bb[i] = *reinterpret_cast<const bf16x8*>(ArdB + i * 16 * 32);
#pragma unroll
    for (int i = 0; i < 4; ++i)
#pragma unroll
      for (int j = 0; j < 4; ++j)
        acc[i][j] = __builtin_amdgcn_mfma_f32_16x16x32_bf16(af[i], bb[j], acc[i][j], 0, 0, 0);
    __syncthreads();
  }

  const int cr = lane >> 4, cc = lane & 15;
#pragma unroll
  for (int i = 0; i < 4; ++i) {
#pragma unroll
    for (int j = 0; j < 4; ++j) {
#pragma unroll
      for (int q = 0; q < 4; ++q) {
        int grow = m0 + wm * 64 + i * 16 + cr * 4 + q;
        int gcol = n0 + wn * 64 + j * 16 + cc;
        float v = acc[i][j][q];
        if (EPI == 0) {
          Cf[(size_t)grow * GNC + gcol] = v;
        } else {
          // grow = n, gcol = p. WfT[n,p] = acc + diag[n]*W1[p,n] + uW[p] - empty[n]*W2[p,n]/NN
          v += uW[gcol];
          float d = diag[grow];
          if (d != 0.f) v += d * W1f[(size_t)gcol * NN + grow];
          if (empty[grow]) v -= W2f[(size_t)gcol * NN + grow] * (1.0f / NN);
          Cb[(size_t)grow * GNC + gcol] = f2bf(v);
        }
      }
    }
  }
}

// ---------------------------------------------------------------- launch
extern "C" void kernel_launch(void* const* d_in, const int* in_sizes, int n_in,
                              void* d_out, int out_size, void* d_ws, size_t ws_size,
                              hipStream_t stream) {
  const float* x   = (const float*)d_in[0];  // [8,512,2048] -> [4096][2048]
  const float* W1  = (const float*)d_in[1];  // [2048][2048]
  const float* W2  = (const float*)d_in[2];  // [2048][2048]
  const float* e   = (const float*)d_in[3];  // [nnz]
  const int*   eix = (const int*)d_in[4];    // [nnz] sorted flat indices (int32 per harness)
  const int nnz = in_sizes[3];
  float* out = (float*)d_out;                // [4096][2048] fp32

  char* w = (char*)d_ws;
  ushort* AoffT = (ushort*)w; w += (size_t)NN * NN * 2;    // 8.4 MB  A_off^T bf16 [n][k]
  ushort* WfT   = (ushort*)w; w += (size_t)NN * NN * 2;    // 8.4 MB  Wfused^T bf16 [n][p]
  ushort* W2b   = (ushort*)w; w += (size_t)NN * NN * 2;    // 8.4 MB  W2 bf16 [p][k]
  ushort* xb    = (ushort*)w; w += (size_t)4096 * NN * 2;  // 16.8 MB x bf16 [m][p]
  float*  diag  = (float*)w;  w += NN * 4;
  int*    empt  = (int*)w;    w += NN * 4;
  float*  uW    = (float*)w;  w += NN * 4;
  int*    ecnt  = (int*)w;    w += 256;

  zero_ws_kernel<<<dim3(2048), dim3(256), 0, stream>>>((uint4*)AoffT, uW, ecnt);
  softmax_scatter_kernel<<<dim3(NN), dim3(64), 0, stream>>>(eix, e, nnz, AoffT, diag, empt, ecnt);
  uw_kernel<<<dim3(8), dim3(256), 0, stream>>>(W2, empt, ecnt, uW);
  f32_to_bf16_kernel<<<dim3(2048), dim3(256), 0, stream>>>(W2, W2b, NN * NN / 8);
  f32_to_bf16_kernel<<<dim3(4096), dim3(256), 0, stream>>>(x, xb, 4096 * NN / 8);

  // GEMM2: WfT[n,p] = sum_k AoffT[n,k] * W2b[p,k]  (+ diag/empty epilogue), bf16 out
  gemm_bt_kernel<1><<<dim3(16, 16), dim3(256), 0, stream>>>(
      AoffT, W2b, nullptr, WfT, diag, empt, uW, W1, W2);
  // main: out[m,n] = sum_p xb[m,p] * WfT[n,p], fp32 out
  gemm_bt_kernel<0><<<dim3(16, 32), dim3(256), 0, stream>>>(
      xb, WfT, out, nullptr, nullptr, nullptr, nullptr, nullptr, nullptr);
}